// Round 1
// baseline (959.774 us; speedup 1.0000x reference)
//
#include <hip/hip_runtime.h>
#include <math.h>

#define NB 256      // B
#define NK 1024     // K
#define ND 2048     // D
#define NN 50000    // N

constexpr float T_INV = 1.0f / 0.07f;
constexpr float Z_INV = 1.0f / 52580.0f;
constexpr float MOM   = 0.5f;

// ---------------------------------------------------------------- helpers
__device__ __forceinline__ float blk_reduce_sum256(float v, float* sh) {
    // 256 threads = 4 waves of 64
    #pragma unroll
    for (int o = 32; o > 0; o >>= 1) v += __shfl_down(v, o, 64);
    int lane = threadIdx.x & 63;
    int wid  = threadIdx.x >> 6;
    if (lane == 0) sh[wid] = v;
    __syncthreads();
    float s = sh[0] + sh[1] + sh[2] + sh[3];
    __syncthreads();
    return s;
}

// ------------------------------------------------- 1) features = x / ||x||
// grid = NB blocks x 256 threads; each thread owns 2 float4 (8 floats) of the row
__global__ void k_feat(const float* __restrict__ x, float* __restrict__ feat) {
    __shared__ float sh[4];
    int b = blockIdx.x;
    int t = threadIdx.x;
    const float4* xr = (const float4*)(x + (size_t)b * ND);
    float4 v0 = xr[t];
    float4 v1 = xr[t + 256];
    float ss = v0.x*v0.x + v0.y*v0.y + v0.z*v0.z + v0.w*v0.w
             + v1.x*v1.x + v1.y*v1.y + v1.z*v1.z + v1.w*v1.w;
    float s = blk_reduce_sum256(ss, sh);
    float r = rsqrtf(s);
    float4* fr = (float4*)(feat + (size_t)b * ND);
    fr[t]       = make_float4(v0.x*r, v0.y*r, v0.z*r, v0.w*r);
    fr[t + 256] = make_float4(v1.x*r, v1.y*r, v1.z*r, v1.w*r);
}

// --------------------------------- 2) out[b,k] = exp(dot(mem[row], feat[b])/T)/Z
// One wave per dot. Lane i handles float4 positions i + 64*j, j=0..7 (D=2048).
// Feature fragment lives in 8 float4 registers (reused across KPW dots).
#define KPW 16   // dots per wave
#define WPB 4    // waves per block (256 threads)
__global__ void k_dots(const float* __restrict__ mem, const float* __restrict__ feat,
                       const int* __restrict__ idx, const int* __restrict__ y,
                       float* __restrict__ out) {
    int wave = threadIdx.x >> 6;
    int lane = threadIdx.x & 63;
    const int bpb = NK / (KPW * WPB);            // blocks per b = 16
    int b  = blockIdx.x / bpb;
    int k0 = (blockIdx.x % bpb) * (KPW * WPB) + wave * KPW;

    const float4* f4 = (const float4*)(feat + (size_t)b * ND);
    float4 ff[8];
    #pragma unroll
    for (int j = 0; j < 8; ++j) ff[j] = f4[lane + 64 * j];

    const int* idxrow = idx + (size_t)b * NK;
    for (int i = 0; i < KPW; ++i) {
        int k = k0 + i;
        int row = (k == 0) ? y[b] : idxrow[k];   // idx[:,0] replaced by y
        const float4* m4 = (const float4*)(mem + (size_t)row * ND);
        float acc = 0.f;
        #pragma unroll
        for (int j = 0; j < 8; ++j) {
            float4 m = m4[lane + 64 * j];
            acc += m.x*ff[j].x + m.y*ff[j].y + m.z*ff[j].z + m.w*ff[j].w;
        }
        #pragma unroll
        for (int o = 32; o > 0; o >>= 1) acc += __shfl_down(acc, o, 64);
        if (lane == 0)
            out[(size_t)b * NK + k] = expf(acc * T_INV) * Z_INV;
    }
}

// ------------------------------------------------- 3) temp = copy of memory
// one float4 per thread, exact grid (NN*ND/4 = 25,600,000 = 100000 * 256)
__global__ void k_copy(const float* __restrict__ mem, float* __restrict__ temp) {
    size_t i = (size_t)blockIdx.x * 256 + threadIdx.x;
    ((float4*)temp)[i] = ((const float4*)mem)[i];
}

// ---------------------- 4) temp[y[b]] = normalize(MOM*mem[y[b]] + (1-MOM)*feat[b])
// last-write-wins on duplicate y (numpy fancy-assignment semantics)
__global__ void k_scatter(const float* __restrict__ mem, const float* __restrict__ feat,
                          const int* __restrict__ y, float* __restrict__ temp) {
    __shared__ float sh[4];
    int b  = blockIdx.x;
    int yb = y[b];
    for (int b2 = b + 1; b2 < NB; ++b2)
        if (y[b2] == yb) return;                 // uniform across block: safe
    int t = threadIdx.x;
    const float4* f4 = (const float4*)(feat + (size_t)b * ND);
    const float4* m4 = (const float4*)(mem  + (size_t)yb * ND);
    float4 f0 = f4[t], f1 = f4[t + 256];
    float4 m0 = m4[t], m1 = m4[t + 256];
    float4 w0 = make_float4(m0.x*MOM + f0.x*(1.f-MOM), m0.y*MOM + f0.y*(1.f-MOM),
                            m0.z*MOM + f0.z*(1.f-MOM), m0.w*MOM + f0.w*(1.f-MOM));
    float4 w1 = make_float4(m1.x*MOM + f1.x*(1.f-MOM), m1.y*MOM + f1.y*(1.f-MOM),
                            m1.z*MOM + f1.z*(1.f-MOM), m1.w*MOM + f1.w*(1.f-MOM));
    float ss = w0.x*w0.x + w0.y*w0.y + w0.z*w0.z + w0.w*w0.w
             + w1.x*w1.x + w1.y*w1.y + w1.z*w1.z + w1.w*w1.w;
    float s = blk_reduce_sum256(ss, sh);
    float r = rsqrtf(s);
    float4* d = (float4*)(temp + (size_t)yb * ND);
    d[t]       = make_float4(w0.x*r, w0.y*r, w0.z*r, w0.w*r);
    d[t + 256] = make_float4(w1.x*r, w1.y*r, w1.z*r, w1.w*r);
}

// ---------------------------------------------------------------- launch
extern "C" void kernel_launch(void* const* d_in, const int* in_sizes, int n_in,
                              void* d_out, int out_size, void* d_ws, size_t ws_size,
                              hipStream_t stream) {
    (void)in_sizes; (void)n_in; (void)out_size; (void)ws_size;
    const float* x   = (const float*)d_in[0];
    const int*   y   = (const int*)d_in[1];
    const int*   idx = (const int*)d_in[2];
    const float* mem = (const float*)d_in[3];

    float* out  = (float*)d_out;                       // [B*K]
    float* temp = (float*)d_out + (size_t)NB * NK;     // [N*D]
    float* feat = (float*)d_ws;                        // [B*D] = 2 MB scratch

    k_feat<<<NB, 256, 0, stream>>>(x, feat);
    k_dots<<<(NB * NK) / (KPW * WPB), 256, 0, stream>>>(mem, feat, idx, y, out);
    k_copy<<<(NN * ND / 4) / 256, 256, 0, stream>>>(mem, temp);
    k_scatter<<<NB, 256, 0, stream>>>(mem, feat, y, temp);
}